// Round 6
// baseline (1848.229 us; speedup 1.0000x reference)
//
#include <hip/hip_runtime.h>

// Persistent-kernel LSTM: B=128, T=512, D=512, H=512, FORGET_BIAS=1.0
// 128 wgs x 512 thr. wg (mg=wgid&7, hb=wgid>>3): rows 16mg..+16, h-cols
// 32hb..+32. Wave w: h-col sub-block w*4..w*4+4, ALL 4 gates (B-frag col
// cb = gate*4 + hc). W resident in VGPR/AGPR (32 frags/wave).
//
// R10 = R8's proven u32 poison handoff (8 slots, 1 MB) + R9's in-wave gate
// transpose (no zbuf, no wg barrier before publish) + vmcnt-queue hygiene:
//  * vmcnt retires IN ORDER (m135) => a poll check (vmcnt(0) on newest
//    loads) waits for ALL older outstanding vmem. So: xissue at phase-A TOP
//    (x flight retires under MFMAs); out-store and repoison AFTER
//    wait_stage (never ahead of a poll check).
//  * deferred repoison: at step t poison slot (t+7)&7 (= h[t-1]'s slot).
//    Safety: passing step t-1's end-barrier => my waves staged h[t] => all
//    16 producers published h[t] => every wg completed step t-2 phase B
//    (the last reads of h[t-1]). Kills the mid-phase-B LBAR entirely.
//    Poison->republish gap = 6 steps, always contains a full-drain step
//    (every 4th step __syncthreads). Publish->poison gap = 2 steps
//    (~13000cy >> ~1000cy store flight).
//  * hlds double-buffered => exactly ONE barrier per step.
// Fail-fast poll caps kept: protocol failure -> wrong data (passed:false),
// never a hung dispatch.

#define B_ 128
#define T_ 512
#define D_ 512
#define H_ 512
#define POISON 0xFFFFFFFFu
#define POLL_CAP 8192

typedef __bf16 bf16x8 __attribute__((ext_vector_type(8)));
typedef float f32x4 __attribute__((ext_vector_type(4)));
typedef unsigned long long u64;

static __device__ __forceinline__ unsigned short f2bf(float f) {
  return __builtin_bit_cast(unsigned short, (__bf16)f);
}
static __device__ __forceinline__ float fast_sigmoid(float x) {
  return __builtin_amdgcn_rcpf(1.f + __expf(-x));
}
static __device__ __forceinline__ float fast_tanh(float x) {
  float xc = fminf(fmaxf(x, -15.f), 15.f);
  float t = __expf(-2.f * xc);
  return (1.f - t) * __builtin_amdgcn_rcpf(1.f + t);
}
static __device__ __forceinline__ bool clean64(u64 v) {
  return ((unsigned int)v != POISON) && ((unsigned int)(v >> 32) != POISON);
}

// lgkm-only barrier: does NOT drain vmcnt (publish/out/x-prefetch/poison
// stores stay in flight). asm memory clobbers pin op order on both sides.
#define LBAR()                                             \
  do {                                                     \
    __asm__ volatile("s_waitcnt lgkmcnt(0)" ::: "memory"); \
    __builtin_amdgcn_s_barrier();                          \
    __asm__ volatile("" ::: "memory");                     \
  } while (0)

// ---- pack W [1024][2048] fp32 -> bf16 B-frag layout (R9 mapping) ----
// frag f = (hb*8 + w)*32 + kt;  Wp[(f*64+lane)*8 + j] = bf16(W[k][col])
//   k = kt*32 + (lane>>4)*8 + j
//   cb = lane&15;  col = (cb>>2)*512 + hb*32 + w*4 + (cb&3)
__global__ __launch_bounds__(256) void pack_w_kernel(const float* __restrict__ W,
                                                     unsigned short* __restrict__ Wp) {
  int tid = blockIdx.x * 256 + threadIdx.x;  // [0, 2^21)
  int j = tid & 7;
  int lane = (tid >> 3) & 63;
  int f = tid >> 9;
  int kt = f & 31;
  int w = (f >> 5) & 7;
  int hb = f >> 8;
  int k = (kt << 5) + ((lane >> 4) << 3) + j;
  int cb = lane & 15;
  int col = ((cb >> 2) << 9) + (hb << 5) + (w << 2) + (cb & 3);
  Wp[tid] = f2bf(W[k * 2048 + col]);
}

// poison hg: 8 slots x 8 groups x 4096 u32 = 1 MB
__global__ __launch_bounds__(1024) void init_ws_kernel(unsigned int* __restrict__ hg) {
  hg[blockIdx.x * 1024 + threadIdx.x] = POISON;
}

__global__ __launch_bounds__(512, 2) void lstm_persistent(
    const float* __restrict__ wv, const int* __restrict__ nw,
    const float* __restrict__ ic, const float* __restrict__ ih,
    const float* __restrict__ bias, const unsigned short* __restrict__ Wp,
    unsigned int* __restrict__ hg, float* __restrict__ out) {
  __shared__ __align__(16) unsigned short hlds[2][16 * 512];   // 32 KB (dbuf)
  __shared__ __align__(16) unsigned short xlds[2][16 * 512];   // 32 KB

  const int tid = threadIdx.x;
  const int wgid = blockIdx.x;
  const int mg = wgid & 7;   // row group
  const int hb = wgid >> 3;  // h-col block
  const int w = tid >> 6;    // wave 0..7
  const int lane = tid & 63;

  // per-lane cell (post-transpose): row er = q*4+gp, hcol kin = w*4+hc
  const int q = lane >> 4;
  const int gp = (lane >> 2) & 3;
  const int hc = lane & 3;
  const int er = (q << 2) + gp;
  const int kin = (w << 2) | hc;   // 0..31
  const int grow = (mg << 4) + er;
  const int gcol = (hb << 5) + kin;

  const int nwv = nw[grow];
  float c_reg = ic[grow * H_ + gcol];
  float h_reg = ih[grow * H_ + gcol];

  // W B-frags: kt 0..15 x-part (rows 0..511), 16..31 h-part
  uint4 wfrag[32];
  {
    const uint4* wp = (const uint4*)Wp + (size_t)((hb * 8 + w) * 32) * 64 + lane;
#pragma unroll
    for (int kt = 0; kt < 32; ++kt) wfrag[kt] = wp[kt * 64];
  }
  // bias for this lane's PRE-transpose accumulator column cb=(gp<<2)|hc
  const float bv = bias[(gp << 9) + (hb << 5) + kin];

  // 8 rotating u32 slots; slot s for group mg: 16 KB at hg + (s*8+mg)*4096
  auto slotp = [&](int s) { return hg + (size_t)(s * 8 + mg) * 4096; };

  // h cell slot (bf16 idx): producer hb owns u16 [hb*512, hb*512+512)
  const int hslot = (hb << 9) + ((er | ((kin >> 3) << 4)) << 3) + (kin & 7);

  auto publish_h = [&](unsigned int* dst) {
    unsigned int hv = (unsigned int)f2bf(h_reg);
    unsigned int up = (unsigned int)__shfl_down((int)hv, 1);
    if ((lane & 1) == 0)
      __hip_atomic_store(dst + (hslot >> 1), hv | (up << 16), __ATOMIC_RELAXED,
                         __HIP_MEMORY_SCOPE_AGENT);
  };

  // Poll-the-data staging: wave w owns producers/k-tiles {2w, 2w+1}.
  // Iteration-capped (fail-fast). NOTE: no older vmem may be outstanding
  // when this runs (vmcnt retires in order — the check waits for it all).
  auto wait_stage = [&](const unsigned int* slot, unsigned short* dstlds) {
    const u64* s = (const u64*)slot;
    const u64* p0 = s + ((2 * w) << 7) + lane;
    const u64* p1 = p0 + 64;
    const u64* p2 = s + ((2 * w + 1) << 7) + lane;
    const u64* p3 = p2 + 64;
    u64 a0, a1, b0, b1;
    int it = 0;
    while (true) {
      a0 = __hip_atomic_load(p0, __ATOMIC_RELAXED, __HIP_MEMORY_SCOPE_AGENT);
      a1 = __hip_atomic_load(p1, __ATOMIC_RELAXED, __HIP_MEMORY_SCOPE_AGENT);
      b0 = __hip_atomic_load(p2, __ATOMIC_RELAXED, __HIP_MEMORY_SCOPE_AGENT);
      b1 = __hip_atomic_load(p3, __ATOMIC_RELAXED, __HIP_MEMORY_SCOPE_AGENT);
      if (__all(clean64(a0) && clean64(a1) && clean64(b0) && clean64(b1))) break;
      if (++it > POLL_CAP) break;
      if (it > 8) __builtin_amdgcn_s_sleep(1);  // busy-poll first
    }
    u64* d = (u64*)dstlds;
    d[((2 * w) << 7) + lane] = a0;
    d[((2 * w) << 7) + 64 + lane] = a1;
    d[((2 * w + 1) << 7) + lane] = b0;
    d[((2 * w + 1) << 7) + 64 + lane] = b1;
  };

  auto repoison = [&](unsigned int* slot) {
    if (tid < 256)
      __hip_atomic_store(slot + (hb << 8) + tid, POISON, __ATOMIC_RELAXED,
                         __HIP_MEMORY_SCOPE_AGENT);
  };

  // T14 split x staging: issue global->regs at phase-A TOP, commit at B end.
  float4 xr[4];
  auto xissue = [&](int tt) {
    if (tt >= T_) return;
#pragma unroll
    for (int s2 = 0; s2 < 2; ++s2) {
      int e = tid + (s2 << 9);
      int ktx = e >> 6;
      int le = e & 63;
      int r = le & 15;
      int d = (ktx << 5) + ((le >> 4) << 3);
      const float* src = wv + ((size_t)((mg << 4) + r) * T_ + tt) * D_ + d;
      xr[2 * s2] = *(const float4*)src;
      xr[2 * s2 + 1] = *(const float4*)(src + 4);
    }
  };
  auto xcommit = [&](int buf, int tt) {
    if (tt >= T_) return;
#pragma unroll
    for (int s2 = 0; s2 < 2; ++s2) {
      int e = tid + (s2 << 9);
      int ktx = e >> 6;
      int le = e & 63;
      float4 xa = xr[2 * s2], xb = xr[2 * s2 + 1];
      bf16x8 v;
      v[0] = (__bf16)xa.x; v[1] = (__bf16)xa.y; v[2] = (__bf16)xa.z; v[3] = (__bf16)xa.w;
      v[4] = (__bf16)xb.x; v[5] = (__bf16)xb.y; v[6] = (__bf16)xb.z; v[7] = (__bf16)xb.w;
      *(bf16x8*)&xlds[buf][(ktx << 9) + (le << 3)] = v;
    }
  };

  // x-part: two persistent accumulator chains (depth 8 each), consumed
  // directly by phase A's 4-chain reduction.
  f32x4 xA, xB;
  auto xpart = [&](int buf) {
    f32x4 A = {0.f, 0.f, 0.f, 0.f};
    f32x4 Bc = {0.f, 0.f, 0.f, 0.f};
#pragma unroll
    for (int kt = 0; kt < 8; ++kt) {
      bf16x8 a0 = *(const bf16x8*)&xlds[buf][(kt << 9) + (lane << 3)];
      bf16x8 a1 = *(const bf16x8*)&xlds[buf][((kt + 8) << 9) + (lane << 3)];
      A = __builtin_amdgcn_mfma_f32_16x16x32_bf16(
          a0, __builtin_bit_cast(bf16x8, wfrag[kt]), A, 0, 0, 0);
      Bc = __builtin_amdgcn_mfma_f32_16x16x32_bf16(
          a1, __builtin_bit_cast(bf16x8, wfrag[kt + 8]), Bc, 0, 0, 0);
    }
    xA = A;
    xB = Bc;
  };

  // ---- prologue: x[0]->buf0, x[1]->buf1, hlds[0] <- bf16(ih) directly ----
  xissue(0); xcommit(0, 0);
  xissue(1); xcommit(1, 1);
#pragma unroll
  for (int s2 = 0; s2 < 2; ++s2) {
    int e = tid + (s2 << 9);
    int ktx = e >> 6;
    int le = e & 63;
    int r = le & 15;
    int d = (ktx << 5) + ((le >> 4) << 3);
    const float* src = ih + (size_t)((mg << 4) + r) * H_ + d;
    float4 ha = *(const float4*)src;
    float4 hbv = *(const float4*)(src + 4);
    bf16x8 v;
    v[0] = (__bf16)ha.x; v[1] = (__bf16)ha.y; v[2] = (__bf16)ha.z; v[3] = (__bf16)ha.w;
    v[4] = (__bf16)hbv.x; v[5] = (__bf16)hbv.y; v[6] = (__bf16)hbv.z; v[7] = (__bf16)hbv.w;
    *(bf16x8*)&hlds[0][(ktx << 9) + (le << 3)] = v;
  }
  __syncthreads();
  xpart(0);

  for (int t = 0; t < T_; ++t) {
    const int par = t & 1;
    unsigned int* hdst = slotp((t + 1) & 7);  // h[t+1]'s slot

    xissue(t + 2);  // HBM loads retire under phase A (pre-poll queue clean)

    // ---- phase A (critical path): h-MFMAs (4 chains of 4) on hlds[par] ----
    const unsigned short* hsrc = hlds[par];
    f32x4 c0 = xA, c1 = xB;
    f32x4 c2 = {0.f, 0.f, 0.f, 0.f};
    f32x4 c3 = {0.f, 0.f, 0.f, 0.f};
#pragma unroll
    for (int i = 0; i < 4; ++i) {
      bf16x8 a0 = *(const bf16x8*)&hsrc[((4 * i) << 9) + (lane << 3)];
      bf16x8 a1 = *(const bf16x8*)&hsrc[((4 * i + 1) << 9) + (lane << 3)];
      bf16x8 a2 = *(const bf16x8*)&hsrc[((4 * i + 2) << 9) + (lane << 3)];
      bf16x8 a3 = *(const bf16x8*)&hsrc[((4 * i + 3) << 9) + (lane << 3)];
      c0 = __builtin_amdgcn_mfma_f32_16x16x32_bf16(
          a0, __builtin_bit_cast(bf16x8, wfrag[16 + 4 * i]), c0, 0, 0, 0);
      c1 = __builtin_amdgcn_mfma_f32_16x16x32_bf16(
          a1, __builtin_bit_cast(bf16x8, wfrag[17 + 4 * i]), c1, 0, 0, 0);
      c2 = __builtin_amdgcn_mfma_f32_16x16x32_bf16(
          a2, __builtin_bit_cast(bf16x8, wfrag[18 + 4 * i]), c2, 0, 0, 0);
      c3 = __builtin_amdgcn_mfma_f32_16x16x32_bf16(
          a3, __builtin_bit_cast(bf16x8, wfrag[19 + 4 * i]), c3, 0, 0, 0);
    }

    // ---- in-wave gates: z per reg, 4x4 (reg <-> lane[3:2]) transpose ----
    float z0 = (c0[0] + c1[0]) + (c2[0] + c3[0]) + bv;
    float z1 = (c0[1] + c1[1]) + (c2[1] + c3[1]) + bv;
    float z2 = (c0[2] + c1[2]) + (c2[2] + c3[2]) + bv;
    float z3 = (c0[3] + c1[3]) + (c2[3] + c3[3]) + bv;
    {
      bool b0 = gp & 1;  // lane bit 2
      float e;
      e = __shfl_xor(b0 ? z0 : z1, 4); if (b0) z0 = e; else z1 = e;
      e = __shfl_xor(b0 ? z2 : z3, 4); if (b0) z2 = e; else z3 = e;
      bool b1 = (gp >> 1) & 1;  // lane bit 3
      e = __shfl_xor(b1 ? z0 : z2, 8); if (b1) z0 = e; else z2 = e;
      e = __shfl_xor(b1 ? z1 : z3, 8); if (b1) z1 = e; else z3 = e;
    }
    // now lane holds z[row=er][gates i,j,f,o] = z0..z3 for hcol=gcol
    float outv;
    {
      float si = fast_sigmoid(z0);
      float tj = fast_tanh(z1);
      float sf = fast_sigmoid(z2 + 1.f);  // FORGET_BIAS
      float so = fast_sigmoid(z3);
      float nc = c_reg * sf + si * tj;
      float nh = fast_tanh(nc) * so;
      bool m = t < nwv;
      c_reg = m ? nc : c_reg;
      h_reg = m ? nh : h_reg;
      outv = m ? nh : 0.f;
      if (t + 1 < T_) publish_h(hdst);  // per-wave, right after own MFMAs
    }

    // ---- phase B (overlap): x-part of t+1, poll+stage h[t+1], then the
    //      deferred stores (out, repoison, xcommit) AFTER the poll ----
    if (t + 1 < T_) {
      xpart(1 - par);                       // x[t+1]; hides publish flight
      wait_stage(hdst, hlds[par ^ 1]);      // poll+stage h[t+1]
    }
    out[(size_t)t * (B_ * H_) + grow * H_ + gcol] = outv;
    if (t + 1 < T_) {
      repoison(slotp((t + 7) & 7));  // h[t-1]'s slot; republished step t+6
      xcommit(par, t + 2);           // regs -> xlds[par]
    }
    // single per-step barrier; full vmcnt drain every 4th step (orders each
    // poison ahead of its slot's republish 6 steps later).
    if ((t & 3) == 3) __syncthreads(); else LBAR();
  }

  size_t base = (size_t)T_ * (B_ * H_);
  out[base + grow * H_ + gcol] = c_reg;
  out[base + B_ * H_ + grow * H_ + gcol] = h_reg;
}

extern "C" void kernel_launch(void* const* d_in, const int* in_sizes, int n_in,
                              void* d_out, int out_size, void* d_ws, size_t ws_size,
                              hipStream_t stream) {
  const float* wv = (const float*)d_in[0];    // [B,T,D]
  const int* nw = (const int*)d_in[1];        // [B]
  const float* ic = (const float*)d_in[2];    // [B,H]
  const float* ih = (const float*)d_in[3];    // [B,H]
  const float* W = (const float*)d_in[4];     // [D+H, 4H]
  const float* bias = (const float*)d_in[5];  // [4H]
  float* out = (float*)d_out;

  char* ws = (char*)d_ws;
  unsigned short* Wp = (unsigned short*)ws;             // 4 MB packed W
  unsigned int* hg = (unsigned int*)(ws + (4u << 20));  // 1 MB: 8 slots x 8 groups x 16 KB

  init_ws_kernel<<<256, 1024, 0, stream>>>(hg);
  pack_w_kernel<<<(1 << 21) / 256, 256, 0, stream>>>(W, Wp);
  lstm_persistent<<<128, 512, 0, stream>>>(wv, nw, ic, ih, bias, Wp, hg, out);
}